// Round 1
// baseline (667.569 us; speedup 1.0000x reference)
//
#include <hip/hip_runtime.h>
#include <hip/hip_bf16.h>

// MHA forward: B=4, T=2048, N=1024, H=16, Dh=64.
// Pipeline: convert->bf16, QKV GEMM (MFMA), flash attention (MFMA), proj GEMM.
// All MFMA layouts per verified gfx950 mappings:
//   A-frag: A[m=lane&15][k=quad*8+j]   B-frag: B[k=quad*8+j][n=lane&15]
//   C/D:    D[row=quad*4+reg][col=lane&15]

typedef __attribute__((ext_vector_type(8))) short short8;   // 8 x bf16 (4 VGPR)
typedef __attribute__((ext_vector_type(4))) float f32x4;

#define MFMA16(a, b, c) __builtin_amdgcn_mfma_f32_16x16x32_bf16((a), (b), (c), 0, 0, 0)

__device__ inline unsigned short f2bfu(float f) {
  union { __hip_bfloat16 h; unsigned short u; } cv;
  cv.h = __float2bfloat16(f);
  return cv.u;
}

// ---------------- elementwise fp32 -> bf16 ----------------
__global__ void conv_f32_bf16(const float* __restrict__ src,
                              unsigned short* __restrict__ dst, int n4) {
  int i = blockIdx.x * blockDim.x + threadIdx.x;
  if (i >= n4) return;
  float4 v = ((const float4*)src)[i];
  ushort4 o;
  o.x = f2bfu(v.x); o.y = f2bfu(v.y); o.z = f2bfu(v.z); o.w = f2bfu(v.w);
  ((ushort4*)dst)[i] = o;
}

// ---------------- transpose + convert: dst[c][r] = bf16(src[r][c]) ----------------
__global__ void transpose_bf16(const float* __restrict__ src,
                               __hip_bfloat16* __restrict__ dst, int R, int C) {
  __shared__ float tile[32][33];
  int tx = threadIdx.x, ty = threadIdx.y;          // block (32, 8)
  int c0 = blockIdx.x * 32, r0 = blockIdx.y * 32;
#pragma unroll
  for (int i = 0; i < 32; i += 8)
    tile[ty + i][tx] = src[(long)(r0 + ty + i) * C + c0 + tx];
  __syncthreads();
#pragma unroll
  for (int i = 0; i < 32; i += 8)
    dst[(long)(c0 + ty + i) * R + r0 + tx] = __float2bfloat16(tile[tx][ty + i]);
}

// ---------------- GEMM: C[M,N] = A[M,K] @ Bt[N,K]^T + bias ----------------
// EPI=0: scatter bf16 into Q[B,H,T,Dh], K[B,H,T,Dh], Vt[B,H,Dh,T]
// EPI=1: write fp32 to out
template <int EPI>
__global__ __launch_bounds__(256, 2) void gemm_bt(
    const __hip_bfloat16* __restrict__ A, const __hip_bfloat16* __restrict__ Bt,
    const float* __restrict__ bias, void* o0, void* o1, void* o2, int N, int K) {
  // LDS tiles as [row][chunk-of-8-bf16], xor-swizzled chunk to avoid 128B-stride conflicts
  __shared__ short8 As[128][8];
  __shared__ short8 Bs[128][8];
  const int tid = threadIdx.x;
  const int lane = tid & 63, w = tid >> 6;
  const int l15 = lane & 15, quad = lane >> 4;
  const int wm = (w >> 1) * 64, wn = (w & 1) * 64;   // wave sub-tile origin in 128x128
  const int rowBase = blockIdx.y * 128;
  const int colBase = blockIdx.x * 128;
  const int srow = tid >> 3, schunk = tid & 7;       // staging: 8 chunks per row

  f32x4 acc[4][4];
#pragma unroll
  for (int mi = 0; mi < 4; ++mi)
#pragma unroll
    for (int ni = 0; ni < 4; ++ni)
      acc[mi][ni] = {0.f, 0.f, 0.f, 0.f};

  for (int k0 = 0; k0 < K; k0 += 64) {
    __syncthreads();
#pragma unroll
    for (int p = 0; p < 4; ++p) {
      int row = p * 32 + srow;
      As[row][schunk ^ (row & 7)] =
          *(const short8*)(A + (rowBase + row) * K + k0 + schunk * 8);
      Bs[row][schunk ^ (row & 7)] =
          *(const short8*)(Bt + (colBase + row) * K + k0 + schunk * 8);
    }
    __syncthreads();
#pragma unroll
    for (int kc = 0; kc < 2; ++kc) {
      short8 af[4], bf[4];
#pragma unroll
      for (int mi = 0; mi < 4; ++mi) {
        int row = wm + mi * 16 + l15;
        af[mi] = As[row][(kc * 4 + quad) ^ (row & 7)];
      }
#pragma unroll
      for (int ni = 0; ni < 4; ++ni) {
        int row = wn + ni * 16 + l15;
        bf[ni] = Bs[row][(kc * 4 + quad) ^ (row & 7)];
      }
#pragma unroll
      for (int mi = 0; mi < 4; ++mi)
#pragma unroll
        for (int ni = 0; ni < 4; ++ni)
          acc[mi][ni] = MFMA16(af[mi], bf[ni], acc[mi][ni]);
    }
  }

  // epilogue
#pragma unroll
  for (int mi = 0; mi < 4; ++mi) {
#pragma unroll
    for (int ni = 0; ni < 4; ++ni) {
#pragma unroll
      for (int r = 0; r < 4; ++r) {
        int grow = rowBase + wm + mi * 16 + quad * 4 + r;
        int gcol = colBase + wn + ni * 16 + l15;
        float v = acc[mi][ni][r] + bias[gcol];
        if (EPI == 0) {
          __hip_bfloat16 bv = __float2bfloat16(v);
          int b = grow >> 11, t = grow & 2047;          // T = 2048
          int which = gcol >> 10, n1 = gcol & 1023;     // N = 1024
          int h = n1 >> 6, d = n1 & 63;                 // Dh = 64
          int bh = b * 16 + h;
          if (which == 0)
            ((__hip_bfloat16*)o0)[(bh * 2048 + t) * 64 + d] = bv;       // Q[B,H,T,Dh]
          else if (which == 1)
            ((__hip_bfloat16*)o1)[(bh * 2048 + t) * 64 + d] = bv;       // K[B,H,T,Dh]
          else
            ((__hip_bfloat16*)o2)[(bh * 64 + d) * 2048 + t] = bv;       // Vt[B,H,Dh,T]
        } else {
          ((float*)o0)[(long)grow * N + gcol] = v;
        }
      }
    }
  }
}

// ---------------- flash attention: one wave = 16 q rows, 32-key tiles ----------------
__global__ __launch_bounds__(256) void attn_kernel(
    const __hip_bfloat16* __restrict__ Q, const __hip_bfloat16* __restrict__ K,
    const __hip_bfloat16* __restrict__ Vt, __hip_bfloat16* __restrict__ Y, int T) {
  __shared__ __hip_bfloat16 Pl[4][16][32];   // per-wave P tile (bf16), C->A layout xform
  const int tid = threadIdx.x;
  const int w = tid >> 6, lane = tid & 63, l15 = lane & 15, quad = lane >> 4;
  const int bh = blockIdx.y;                 // b*16 + h
  const int b = bh >> 4, h = bh & 15;
  const __hip_bfloat16* Qp = Q + (long)bh * T * 64;
  const __hip_bfloat16* Kp = K + (long)bh * T * 64;
  const __hip_bfloat16* Vp = Vt + (long)bh * 64 * T;
  const int qrow0 = blockIdx.x * 64 + w * 16;

  // Q fragments stay in registers for the whole loop (Dh=64 -> two K=32 frags)
  short8 q0 = *(const short8*)(Qp + (qrow0 + l15) * 64 + quad * 8);
  short8 q1 = *(const short8*)(Qp + (qrow0 + l15) * 64 + 32 + quad * 8);

  f32x4 oacc[4];
#pragma unroll
  for (int dc = 0; dc < 4; ++dc) oacc[dc] = {0.f, 0.f, 0.f, 0.f};
  float m_r[4], l_r[4];
#pragma unroll
  for (int r = 0; r < 4; ++r) { m_r[r] = -INFINITY; l_r[r] = 0.f; }

  const float cscale = 0.125f * 1.44269504089f;  // 1/sqrt(64) * log2(e): base-2 softmax
  const int nkt = qrow0 / 32 + 1;                // causal: keys <= qrow0+15

  for (int kt = 0; kt < nkt; ++kt) {
    const int kb = kt * 32;
    // S = Q K^T for 16 rows x 32 keys (two 16-key groups)
    f32x4 s0 = {0.f, 0.f, 0.f, 0.f}, s1 = {0.f, 0.f, 0.f, 0.f};
    {
      short8 k00 = *(const short8*)(Kp + (kb + l15) * 64 + quad * 8);
      short8 k01 = *(const short8*)(Kp + (kb + l15) * 64 + 32 + quad * 8);
      s0 = MFMA16(q0, k00, s0);
      s0 = MFMA16(q1, k01, s0);
      short8 k10 = *(const short8*)(Kp + (kb + 16 + l15) * 64 + quad * 8);
      short8 k11 = *(const short8*)(Kp + (kb + 16 + l15) * 64 + 32 + quad * 8);
      s1 = MFMA16(q0, k10, s1);
      s1 = MFMA16(q1, k11, s1);
    }
    // online softmax (per row = quad*4+r, distributed over 16 lanes)
    float alpha[4];
#pragma unroll
    for (int r = 0; r < 4; ++r) {
      int row = qrow0 + quad * 4 + r;
      float a0 = (kb + l15) <= row ? s0[r] * cscale : -INFINITY;
      float a1 = (kb + 16 + l15) <= row ? s1[r] * cscale : -INFINITY;
      float mx = fmaxf(a0, a1);
      mx = fmaxf(mx, __shfl_xor(mx, 1));
      mx = fmaxf(mx, __shfl_xor(mx, 2));
      mx = fmaxf(mx, __shfl_xor(mx, 4));
      mx = fmaxf(mx, __shfl_xor(mx, 8));
      float mnew = fmaxf(m_r[r], mx);
      alpha[r] = exp2f(m_r[r] - mnew);
      m_r[r] = mnew;
      float p0 = exp2f(a0 - mnew);
      float p1 = exp2f(a1 - mnew);
      float rs = p0 + p1;
      rs += __shfl_xor(rs, 1);
      rs += __shfl_xor(rs, 2);
      rs += __shfl_xor(rs, 4);
      rs += __shfl_xor(rs, 8);
      l_r[r] = l_r[r] * alpha[r] + rs;
      // P (C-layout) -> LDS, will be re-read in A-layout (within-wave, no barrier)
      Pl[w][quad * 4 + r][l15] = __float2bfloat16(p0);
      Pl[w][quad * 4 + r][16 + l15] = __float2bfloat16(p1);
    }
#pragma unroll
    for (int dc = 0; dc < 4; ++dc)
#pragma unroll
      for (int r = 0; r < 4; ++r) oacc[dc][r] *= alpha[r];
    short8 pf = *(short8*)&Pl[w][l15][quad * 8];
#pragma unroll
    for (int dc = 0; dc < 4; ++dc) {
      short8 vf = *(const short8*)(Vp + (dc * 16 + l15) * (long)T + kb + quad * 8);
      oacc[dc] = MFMA16(pf, vf, oacc[dc]);
    }
  }

  // Y[B,T,N]: col = h*64 + dc*16 + l15 (contiguous for proj GEMM A-frags)
#pragma unroll
  for (int dc = 0; dc < 4; ++dc)
#pragma unroll
    for (int r = 0; r < 4; ++r) {
      int row = qrow0 + quad * 4 + r;
      Y[((long)(b * 2048 + row)) * 1024 + h * 64 + dc * 16 + l15] =
          __float2bfloat16(oacc[dc][r] / l_r[r]);
    }
}

extern "C" void kernel_launch(void* const* d_in, const int* in_sizes, int n_in,
                              void* d_out, int out_size, void* d_ws, size_t ws_size,
                              hipStream_t stream) {
  const float* x  = (const float*)d_in[0];   // [4,2048,1024]
  const float* Wa = (const float*)d_in[1];   // [1024,3072]
  const float* ba = (const float*)d_in[2];   // [3072]
  const float* Wp = (const float*)d_in[3];   // [1024,1024]
  const float* bp = (const float*)d_in[4];   // [1024]
  float* out = (float*)d_out;                // [4,2048,1024] fp32

  char* ws = (char*)d_ws;
  // workspace map (bytes), all bf16, 16B-aligned; total 92,274,688
  __hip_bfloat16* Xb  = (__hip_bfloat16*)(ws);              // [8192,1024]  16.0 MB
  __hip_bfloat16* WaT = (__hip_bfloat16*)(ws + 16777216);   // [3072,1024]   6.3 MB
  __hip_bfloat16* WpT = (__hip_bfloat16*)(ws + 23068672);   // [1024,1024]   2.1 MB
  __hip_bfloat16* Qb  = (__hip_bfloat16*)(ws + 25165824);   // [B,H,T,Dh]   16.8 MB
  __hip_bfloat16* Kb  = (__hip_bfloat16*)(ws + 41943040);   // [B,H,T,Dh]   16.8 MB
  __hip_bfloat16* Vtb = (__hip_bfloat16*)(ws + 58720256);   // [B,H,Dh,T]   16.8 MB
  __hip_bfloat16* Yb  = (__hip_bfloat16*)(ws + 75497472);   // [8192,1024]  16.8 MB
  if (ws_size < 92274688) return;  // insufficient scratch: fail without corrupting

  conv_f32_bf16<<<8192, 256, 0, stream>>>(x, (unsigned short*)Xb, 2097152);
  transpose_bf16<<<dim3(96, 32), dim3(32, 8), 0, stream>>>(Wa, WaT, 1024, 3072);
  transpose_bf16<<<dim3(32, 32), dim3(32, 8), 0, stream>>>(Wp, WpT, 1024, 1024);
  // QKV: M=8192 (grid.y=64), N=3072 (grid.x=24), K=1024
  gemm_bt<0><<<dim3(24, 64), 256, 0, stream>>>(Xb, WaT, ba, Qb, Kb, Vtb, 3072, 1024);
  // attention: grid = (T/64, B*H)
  attn_kernel<<<dim3(32, 64), 256, 0, stream>>>(Qb, Kb, Vtb, Yb, 2048);
  // proj: M=8192, N=1024, K=1024 -> fp32 out
  gemm_bt<1><<<dim3(8, 64), 256, 0, stream>>>(Yb, WpT, bp, out, nullptr, nullptr, 1024, 1024);
}